// Round 17
// baseline (366.549 us; speedup 1.0000x reference)
//
#include <hip/hip_runtime.h>
#include <hip/hip_bf16.h>
#include <stdint.h>

// ---------------------------------------------------------------------------
// SCINet forward (B=32,T=1024,C=128,HID=512, 3 levels, N_SPLITS=2) on gfx950.
// fp16 MFMA GEMMs, XOR swizzle baked into producers, all-fp16 carry path.
// R17: conv2 retiled 128 rows x 128 cols (512 thr, 8 waves 4x2) -- halves
// the staged-W2-bytes per output row (6KB -> 3KB/row), the binding traffic
// term (conv2 was at ~79% of its delivery floor). A [132][128] 33KB per ck,
// B [128][128] 32KB per (ck,kk); LDS 65KB; grid 256 = 1 blk/CU @ 2 w/SIMD.
// conv1 = R12 weight-stationary form (unchanged).
// ---------------------------------------------------------------------------

static constexpr int B_ = 32, T_ = 1024, C_ = 128, HID_ = 512;
static constexpr int K1_ = 5, K2_ = 3;

typedef __attribute__((ext_vector_type(8))) _Float16 half8;
typedef __attribute__((ext_vector_type(4))) float f32x4;

__device__ __forceinline__ unsigned short f2h(float f) {
    _Float16 h = (_Float16)f;                     // v_cvt_f16_f32 (RNE)
    return __builtin_bit_cast(unsigned short, h);
}

__device__ __forceinline__ float h2f(unsigned short u) {
    return (float)__builtin_bit_cast(_Float16, u);
}

__device__ __forceinline__ void gload16(const void* g, void* l) {
    __builtin_amdgcn_global_load_lds(
        (const __attribute__((address_space(1))) unsigned int*)g,
        (__attribute__((address_space(3))) unsigned int*)l, 16, 0, 0);
}

// ---------------------------------------------------------------------------
// Weight prep: fp32 [slab][CIN][COUT] -> fp16 [slab][COUT][CIN].
// SWZ=true: XOR-swizzle ci within 128-chunks by co&7 (conv2 B, LDS-staged).
// SWZ=false: linear (conv1 loads weights straight to VGPRs).
// ---------------------------------------------------------------------------
template<int CIN, int COUT, bool SWZ>
__global__ __launch_bounds__(256)
void wprep_k(const float* __restrict__ win1, unsigned short* __restrict__ wout1,
             const float* __restrict__ win2, unsigned short* __restrict__ wout2,
             int nhalf) {
    constexpr int TA = CIN / 64, TB = COUT / 64;
    int blk = blockIdx.x;
    int tb = blk % TB;
    int ta = (blk / TB) % TA;
    int s  = blk / (TA * TB);
    const float* win;
    unsigned short* wout;
    if (s < nhalf) { win = win1; wout = wout1; }
    else           { win = win2; wout = wout2; s -= nhalf; }
    __shared__ float tile[64][65];
    const float* src = win + (size_t)s * CIN * COUT;
    unsigned short* dst = wout + (size_t)s * CIN * COUT;
    int cl = threadIdx.x & 63;
    int rw = threadIdx.x >> 6;
    for (int r = rw; r < 64; r += 4)
        tile[r][cl] = src[(size_t)(ta * 64 + r) * COUT + tb * 64 + cl];
    __syncthreads();
    for (int r = rw; r < 64; r += 4) {
        int co = tb * 64 + r;
        int ci = ta * 64 + cl;
        int ciw = SWZ ? ((ci & ~127) | ((ci & 127) ^ ((co & 7) << 3))) : ci;
        dst[(size_t)co * CIN + ciw] = f2h(tile[cl][r]);
    }
}

// ---------------------------------------------------------------------------
// Split (level 0 only): x [B][1024][C] fp32 -> actb [2][B][512][swz(C)] fp16.
// actb swizzle key = (u+4)&7  (conv1 LDS row = u - t0 + 4, t0 % 8 == 0).
// ---------------------------------------------------------------------------
__global__ __launch_bounds__(256)
void split_k(const float* __restrict__ cur, unsigned short* __restrict__ outb,
             int Ls) {
    int idx = blockIdx.x * 256 + threadIdx.x;       // 1,048,576 total (rows*32)
    int row = idx >> 5;
    int cq  = (idx & 31) << 2;
    int BLs = B_ * Ls;
    int g  = row / BLs;
    int r2 = row - g * BLs;
    int b  = r2 / Ls;
    int u  = r2 - b * Ls;
    int p = g >> 1, i = g & 1;
    const float4 v = *(const float4*)(cur +
        ((size_t)(p * B_ + b) * (2 * Ls) + 2 * u + i) * C_ + cq);
    ushort4 o;
    o.x = f2h(v.x); o.y = f2h(v.y); o.z = f2h(v.z); o.w = f2h(v.w);
    int cqw = cq ^ (((u + 4) & 7) << 3);            // 8B-aligned XOR (bits 3-5)
    *(ushort4*)(outb + (size_t)row * C_ + cqw) = o;
}

// ---------------------------------------------------------------------------
// conv1 (weight-stationary, R12 form): out = leaky( conv_K5(in,W)+b1 ).
// 512 blocks (2/CU, resident). breg[5][2][4] half8 loaded once pre-loop;
// A: 2 x [80][128] LDS dbuf; rt sweep rotated by ct.
// Output hid swizzled key (t+2)&7 for conv2's LDS (t0%128==0 -> key r&7).
// ---------------------------------------------------------------------------
__global__ __launch_bounds__(256, 2)
void conv1_k(const unsigned short* __restrict__ actb,
             const unsigned short* __restrict__ wL,   // [widx][5][512][128] LINEAR
             const float* __restrict__ bias,          // [widx][512]
             unsigned short* __restrict__ hid,        // [G][B][Ls][512swz]
             const unsigned short* __restrict__ zp,
             int Ls, int rsplit, int idxbase) {
    __shared__ unsigned short smemA[2][80 * 128];     // 2 x 20 KiB

    const int tid = threadIdx.x;
    const int lane = tid & 63;
    const int w = tid >> 6;
    const int wr = w >> 1, wc = w & 1;

    const int blk = blockIdx.x;
    const int ct = blk & 7;                           // 8 col tiles of 64
    const int rs = (blk >> 3) % rsplit;
    const int g  = (blk >> 3) / rsplit;
    const int n0 = ct * 64;
    const int gin  = g ^ 1;
    const int widx = (idxbase + (g >> 1)) * 2 + (g & 1);

    const char* gbase = (const char*)(actb + (size_t)gin * B_ * Ls * C_);
    const float* bptr = bias + (size_t)widx * HID_;

    const unsigned short* wlane = wL + (size_t)widx * (K1_ * HID_ * C_)
        + (size_t)(n0 + wc * 32 + (lane & 15)) * C_ + ((lane >> 4) << 3);
    half8 breg[K1_][2][4];
#pragma unroll
    for (int t = 0; t < K1_; ++t)
#pragma unroll
        for (int n = 0; n < 2; ++n)
#pragma unroll
            for (int ks = 0; ks < 4; ++ks)
                breg[t][n][ks] = *(const half8*)(wlane
                    + ((size_t)t * HID_ + n * 16) * C_ + ks * 32);

    const float bv0 = bptr[n0 + wc * 32 + (lane & 15)];
    const float bv1 = bptr[n0 + wc * 32 + 16 + (lane & 15)];

    const int rtbase = rs * 8;
    const int i0 = ct & 7;                            // rotation offset

    auto stage = [&](int rt, int p) {
        const int b  = (rt * 64) / Ls;
        const int t0 = (rt * 64) % Ls;
        const char* inb = gbase + (size_t)b * Ls * 256;
#pragma unroll
        for (int j = 0; j < 5; ++j) {
            int ch = w * 5 + j;
            int q = ch * 1024 + lane * 16;
            int r = q >> 8;
            int cb = q & 255;
            int t = t0 - 4 + r;
            const char* src = (t >= 0) ? inb + (size_t)t * 256 + cb
                                       : (const char*)zp + cb;
            gload16(src, (char*)smemA[p] + ch * 1024);
        }
    };

    stage(rtbase + i0, 0);
    asm volatile("s_waitcnt vmcnt(0)" ::: "memory");
    __syncthreads();

#pragma unroll
    for (int i = 0; i < 8; ++i) {
        const int rt = rtbase + ((i + i0) & 7);       // rotated sweep
        const int b  = (rt * 64) / Ls;
        const int t0 = (rt * 64) % Ls;
        const int p  = i & 1;

        __syncthreads();                  // [A] all waves done reading buf[p^1]
        if (i < 7) stage(rtbase + ((i + 1 + i0) & 7), p ^ 1);
        if (i > 0) {
            if (i < 7) {
                asm volatile("s_waitcnt vmcnt(21)" ::: "memory");
            } else {
                asm volatile("s_waitcnt vmcnt(16)" ::: "memory");
            }
            __syncthreads();              // [B] buf[p] fully staged for everyone
        }

        f32x4 acc[2][2];
#pragma unroll
        for (int m = 0; m < 2; ++m)
#pragma unroll
            for (int n = 0; n < 2; ++n) acc[m][n] = (f32x4){0.f, 0.f, 0.f, 0.f};

        const unsigned short* sA = smemA[p];
#pragma unroll
        for (int kk = 0; kk < K1_; ++kk) {
#pragma unroll
            for (int ks = 0; ks < 4; ++ks) {
                half8 aF[2];
                const int cole = ks * 32 + ((lane >> 4) << 3);
#pragma unroll
                for (int m = 0; m < 2; ++m) {
                    int ar = kk + wr * 32 + m * 16 + (lane & 15);
                    aF[m] = *(const half8*)(sA + ar * 128 + (cole ^ ((ar & 7) << 3)));
                }
#pragma unroll
                for (int m = 0; m < 2; ++m) {
                    acc[m][0] = __builtin_amdgcn_mfma_f32_16x16x32_f16(
                        aF[m], breg[kk][0][ks], acc[m][0], 0, 0, 0);
                    acc[m][1] = __builtin_amdgcn_mfma_f32_16x16x32_f16(
                        aF[m], breg[kk][1][ks], acc[m][1], 0, 0, 0);
                }
            }
        }

        unsigned short* outp = hid + ((size_t)(g * B_ + b) * Ls + t0) * HID_;
#pragma unroll
        for (int n = 0; n < 2; ++n) {
            const int co = n0 + wc * 32 + n * 16 + (lane & 15);
            const float bv = n ? bv1 : bv0;
#pragma unroll
            for (int m = 0; m < 2; ++m) {
                const int u0 = wr * 32 + m * 16 + ((lane >> 4) << 2);
#pragma unroll
                for (int q = 0; q < 4; ++q) {
                    float v = acc[m][n][q] + bv;
                    v = (v > 0.f) ? v : 0.01f * v;        // LeakyReLU
                    int t = t0 + u0 + q;
                    int cow = (co & ~127) | ((co & 127) ^ (((t + 2) & 7) << 3));
                    outp[(size_t)(u0 + q) * HID_ + cow] = f2h(v);
                }
            }
        }
    }
}

// ---------------------------------------------------------------------------
// conv2 (R17: 128x128 tile, 512 threads): s = tanh( conv_K3(hid,W2)+b2 )
// 8 waves (wr=w&3 row-quarter of 32, wc=w>>2 col-half of 64); acc[2][4].
// A [132][128] 33KB (rows t0-2..t0+129, swz key r&7), staged per ck;
// B [128][128] 32KB per (ck,kk) round (rotated). LDS 65KB. Grid = 256.
// EPI 0: sv = ain (fp16, swz (u+4)&7); mul = sv*exp(th) -> gout (fp16 swz).
// EPI 1: val = gate +/- th -> actn (fused split, fp16 swz (uq+4)&7).
// EPI 2: val = gate +/- th -> dout (fused rev_split gather, f32).
// ---------------------------------------------------------------------------
template<int EPI>
__global__ __launch_bounds__(512, 2)
void conv2_k(const unsigned short* __restrict__ hid,  // [G][B][Ls][512swz]
             const unsigned short* __restrict__ wT,   // [widx][3][128][512swz]
             const float* __restrict__ bias,          // [widx][128]
             const unsigned short* __restrict__ ain,  // EPI==0: level input (swz)
             const unsigned short* __restrict__ gate, // EPI>=1 (fp16 swz)
             unsigned short* __restrict__ gout,       // EPI==0 out
             unsigned short* __restrict__ actn,       // EPI==1 next-lvl in
             float* __restrict__ dout,                // EPI==2 out
             const unsigned short* __restrict__ zp,
             int Ls, int RT, int idxbase) {
    __shared__ unsigned short smemA[132 * 128];       // 33 KiB
    __shared__ unsigned short smemB[128 * 128];       // 32 KiB

    const int tid = threadIdx.x;
    const int lane = tid & 63;
    const int w = tid >> 6;                           // 0..7
    const int wr = w & 3, wc = w >> 2;
    const int hi8 = (lane >> 4) << 3;
    const int l15 = lane & 15;

    int blk = blockIdx.x;
    const int rt = blk % RT;
    const int g  = blk / RT;
    const int rowstart = rt * 128;
    const int b  = rowstart / Ls;
    const int t0 = rowstart - b * Ls;                 // t0 % 128 == 0
    const int widx = (idxbase + (g >> 1)) * 2 + (g & 1);

    const char* inb = (const char*)(hid + (size_t)(g * B_ + b) * Ls * HID_);
    const char* wb  = (const char*)(wT + (size_t)widx * (K2_ * C_ * HID_));
    const float* bptr = bias + (size_t)widx * C_;

    const int c0 = blk & 3;                           // rotation offsets
    const int k0 = blk % 3;

    // stage A chunk ck: rows t0-2 .. t0+129 (132 rows x 256 B = 33 chunks)
    auto stageA = [&](int ck) {
#pragma unroll
        for (int j = 0; j < 5; ++j) {
            int ch = w + j * 8;
            if (ch < 33) {
                int q = ch * 1024 + lane * 16;
                int r = q >> 8;
                int cb = q & 255;
                int t = t0 - 2 + r;
                const char* src = (t >= 0 && t < Ls)
                    ? inb + (size_t)t * 1024 + ck * 256 + cb
                    : (const char*)zp + cb;
                gload16(src, (char*)smemA + ch * 1024);
            }
        }
    };
    // stage B tile (ck,kk): 128 co rows x 256 B = 32 chunks, 4 per wave
    auto stageB = [&](int ck, int kk) {
        const char* wt = wb + (size_t)kk * C_ * HID_ * 2;
#pragma unroll
        for (int j = 0; j < 4; ++j) {
            int ch = w * 4 + j;
            int q = ch * 1024 + lane * 16;
            int co = q >> 8;
            int cb = q & 255;
            gload16(wt + (size_t)co * 1024 + ck * 256 + cb,
                    (char*)smemB + ch * 1024);
        }
    };

    f32x4 acc[2][4];
#pragma unroll
    for (int m = 0; m < 2; ++m)
#pragma unroll
        for (int n = 0; n < 4; ++n) acc[m][n] = (f32x4){0.f, 0.f, 0.f, 0.f};

    for (int ckp = 0; ckp < 4; ++ckp) {        // rotated chunks over CIN=512
        const int ck = (ckp + c0) & 3;
        for (int kkp = 0; kkp < K2_; ++kkp) {
            const int kk = (kkp + k0) % 3;
            if (ckp | kkp) __syncthreads();    // readers done with smemA/B
            stageB(ck, kk);
            if (kkp == 0) stageA(ck);
            asm volatile("s_waitcnt vmcnt(0)" ::: "memory");
            __syncthreads();

#pragma unroll
            for (int ks = 0; ks < 4; ++ks) {
                half8 aF[2], bF[4];
                const int cole = ks * 32 + hi8;
#pragma unroll
                for (int m = 0; m < 2; ++m) {
                    // local row r = (t - (t0-2)) = wr*32 + m*16 + l15 + kk
                    int ar = kk + wr * 32 + m * 16 + l15;
                    aF[m] = *(const half8*)(smemA + ar * 128 + (cole ^ ((ar & 7) << 3)));
                }
#pragma unroll
                for (int n = 0; n < 4; ++n) {
                    int br = wc * 64 + n * 16 + l15;
                    bF[n] = *(const half8*)(smemB + br * 128 + (cole ^ ((br & 7) << 3)));
                }
#pragma unroll
                for (int m = 0; m < 2; ++m)
#pragma unroll
                    for (int n = 0; n < 4; ++n)
                        acc[m][n] = __builtin_amdgcn_mfma_f32_16x16x32_f16(
                            aF[m], bF[n], acc[m][n], 0, 0, 0);
            }
        }
    }

    const size_t rowb = (size_t)(g * B_ + b) * Ls + t0;
    const int Ls2 = Ls >> 1;
    const int i_ = g & 1;
#pragma unroll
    for (int n = 0; n < 4; ++n) {
        int c = wc * 64 + n * 16 + l15;
        float bv = bptr[c];
#pragma unroll
        for (int m = 0; m < 2; ++m) {
            int u0 = wr * 32 + m * 16 + ((lane >> 4) << 2);
#pragma unroll
            for (int q = 0; q < 4; ++q) {
                float v = acc[m][n][q] + bv;
                float xc = fminf(fmaxf(v, -15.f), 15.f);
                float e2 = __expf(2.f * xc);
                float th = (e2 - 1.f) / (e2 + 1.f);        // tanh
                size_t ro = rowb + (size_t)(u0 + q);
                int u = t0 + u0 + q;                       // local split time
                int cw = c ^ (((u + 4) & 7) << 3);         // fp16-buffer swizzle
                if (EPI == 0) {
                    float sv = h2f(ain[ro * C_ + cw]);     // level input (fp16)
                    float mv = sv * __expf(th);
                    gout[ro * C_ + cw] = f2h(mv);
                } else {
                    float mv = h2f(gate[ro * C_ + cw]);
                    float val = (i_ == 0) ? (mv + th) : (mv - th);
                    if (EPI == 1) {
                        int gq = g * 2 + (u & 1);          // fused split
                        int uq = u >> 1;
                        int cw2 = c ^ (((uq + 4) & 7) << 3);
                        actn[((size_t)(gq * B_ + b) * Ls2 + uq) * C_ + cw2] = f2h(val);
                    } else {
                        int tau = u | (((g >> 2) & 1) << 7) | (((g >> 1) & 1) << 8)
                                    | ((g & 1) << 9);
                        dout[((size_t)b * T_ + tau) * C_ + c] = val;
                    }
                }
            }
        }
    }
}

// ---------------------------------------------------------------------------
extern "C" void kernel_launch(void* const* d_in, const int* in_sizes, int n_in,
                              void* d_out, int out_size, void* d_ws, size_t ws_size,
                              hipStream_t stream) {
    const float* x   = (const float*)d_in[0];
    const float* mw1 = (const float*)d_in[1];
    const float* mb1 = (const float*)d_in[2];
    const float* mw2 = (const float*)d_in[3];
    const float* mb2 = (const float*)d_in[4];
    const float* aw1 = (const float*)d_in[5];
    const float* ab1 = (const float*)d_in[6];
    const float* aw2 = (const float*)d_in[7];
    const float* ab2 = (const float*)d_in[8];

    char* ws = (char*)d_ws;
    size_t off = 0;
    auto alloc = [&](size_t sz) {
        char* p = ws + off;
        off += (sz + 255) & ~(size_t)255;
        return p;
    };
    unsigned short* zp   = (unsigned short*)alloc(8192);
    unsigned short* w1m  = (unsigned short*)alloc((size_t)14 * 5 * 512 * 128 * 2);
    unsigned short* w1a  = (unsigned short*)alloc((size_t)14 * 5 * 512 * 128 * 2);
    unsigned short* w2m  = (unsigned short*)alloc((size_t)14 * 3 * 128 * 512 * 2);
    unsigned short* w2a  = (unsigned short*)alloc((size_t)14 * 3 * 128 * 512 * 2);
    unsigned short* actb = (unsigned short*)alloc((size_t)4194304 * 2);
    unsigned short* actg = (unsigned short*)alloc((size_t)4194304 * 2);
    unsigned short* hidb = (unsigned short*)alloc((size_t)16777216 * 2);
    (void)ws_size; (void)n_in; (void)in_sizes; (void)out_size;

    hipMemsetAsync(zp, 0, 8192, stream);

    // weight prep: w1 LINEAR (conv1 loads to VGPR), w2 swizzled (conv2 LDS)
    wprep_k<128, 512, false><<<2240, 256, 0, stream>>>(mw1, w1m, aw1, w1a, 70);
    wprep_k<512, 128, true ><<<1344, 256, 0, stream>>>(mw2, w2m, aw2, w2a, 42);

    // level-0 split (levels 1,2 fused into conv2-EPI1)
    split_k<<<4096, 256, 0, stream>>>(x, actb, 512);

    for (int lvl = 0; lvl < 3; ++lvl) {
        const int G = 2 << lvl;
        const int Ls = (1024 >> lvl) >> 1;
        const int idxbase = (1 << lvl) - 1;
        const int rsplit = (B_ * Ls / 64) / 8;   // 8 row-tiles per conv1 block
        const int RT2 = B_ * Ls / 128;           // conv2 128-row tiles

        // mul branch: conv1 reads actb -> hidb; conv2<0> reads actb -> actg
        conv1_k<<<512, 256, 0, stream>>>(actb, w1m, mb1, hidb, zp,
                                         Ls, rsplit, idxbase);
        conv2_k<0><<<G * RT2, 512, 0, stream>>>(hidb, w2m, mb2, actb, nullptr,
                                                actg, nullptr, nullptr,
                                                zp, Ls, RT2, idxbase);
        // add branch: conv1 reads actg -> hidb; conv2<1/2> combine from actg
        conv1_k<<<512, 256, 0, stream>>>(actg, w1a, ab1, hidb, zp,
                                         Ls, rsplit, idxbase);
        if (lvl < 2) {
            conv2_k<1><<<G * RT2, 512, 0, stream>>>(hidb, w2a, ab2, nullptr, actg,
                                                    nullptr, actb, nullptr,
                                                    zp, Ls, RT2, idxbase);
        } else {
            conv2_k<2><<<G * RT2, 512, 0, stream>>>(hidb, w2a, ab2, nullptr, actg,
                                                    nullptr, nullptr, (float*)d_out,
                                                    zp, Ls, RT2, idxbase);
        }
    }
}

// Round 18
// 356.221 us; speedup vs baseline: 1.0290x; 1.0290x over previous
//
#include <hip/hip_runtime.h>
#include <hip/hip_bf16.h>
#include <stdint.h>

// ---------------------------------------------------------------------------
// SCINet forward (B=32,T=1024,C=128,HID=512, 3 levels, N_SPLITS=2) on gfx950.
// fp16 MFMA GEMMs, XOR swizzle baked into producers, all-fp16 carry path.
// R18: conv2 reverted to R16 form (R17's 128-row tile lost 2-blk/CU TLP).
// Prep merged: wprep(w1) + wprep(w2) + split in ONE launch (13 total).
// conv1 = weight-stationary (R12); conv2 = 64x128 (256,3) + fp16 carry.
// ---------------------------------------------------------------------------

static constexpr int B_ = 32, T_ = 1024, C_ = 128, HID_ = 512;
static constexpr int K1_ = 5, K2_ = 3;

typedef __attribute__((ext_vector_type(8))) _Float16 half8;
typedef __attribute__((ext_vector_type(4))) float f32x4;

__device__ __forceinline__ unsigned short f2h(float f) {
    _Float16 h = (_Float16)f;                     // v_cvt_f16_f32 (RNE)
    return __builtin_bit_cast(unsigned short, h);
}

__device__ __forceinline__ float h2f(unsigned short u) {
    return (float)__builtin_bit_cast(_Float16, u);
}

__device__ __forceinline__ void gload16(const void* g, void* l) {
    __builtin_amdgcn_global_load_lds(
        (const __attribute__((address_space(1))) unsigned int*)g,
        (__attribute__((address_space(3))) unsigned int*)l, 16, 0, 0);
}

// ---------------------------------------------------------------------------
// prep_k: one launch, three block-uniform roles.
//   [0, 2240):    w1 prep  fp32 [s][128][512] -> fp16 [s][512][128] LINEAR
//   [2240, 3584): w2 prep  fp32 [s][512][128] -> fp16 [s][128][512] SWZ co&7
//   [3584, 7680): level-0 split x -> actb (fp16, swz (u+4)&7)
// ---------------------------------------------------------------------------
__global__ __launch_bounds__(256)
void prep_k(const float* __restrict__ mw1, unsigned short* __restrict__ w1m,
            const float* __restrict__ aw1, unsigned short* __restrict__ w1a,
            const float* __restrict__ mw2, unsigned short* __restrict__ w2m,
            const float* __restrict__ aw2, unsigned short* __restrict__ w2a,
            const float* __restrict__ x,   unsigned short* __restrict__ actb) {
    __shared__ float tile[64][65];
    const int blk = blockIdx.x;
    const int tid = threadIdx.x;

    if (blk < 3584) {
        // -------- weight transpose prep --------
        int CIN, COUT, TB, TA, nhalf, sub;
        bool swz;
        const float* win1; const float* win2;
        unsigned short* wout1; unsigned short* wout2;
        if (blk < 2240) {
            sub = blk; CIN = 128; COUT = 512; TA = 2; TB = 8; nhalf = 70;
            swz = false; win1 = mw1; wout1 = w1m; win2 = aw1; wout2 = w1a;
        } else {
            sub = blk - 2240; CIN = 512; COUT = 128; TA = 8; TB = 2; nhalf = 42;
            swz = true;  win1 = mw2; wout1 = w2m; win2 = aw2; wout2 = w2a;
        }
        int tb = sub % TB;
        int ta = (sub / TB) % TA;
        int s  = sub / (TA * TB);
        const float* win; unsigned short* wout;
        if (s < nhalf) { win = win1; wout = wout1; }
        else           { win = win2; wout = wout2; s -= nhalf; }
        const float* src = win + (size_t)s * CIN * COUT;
        unsigned short* dst = wout + (size_t)s * CIN * COUT;
        int cl = tid & 63;
        int rw = tid >> 6;
        for (int r = rw; r < 64; r += 4)
            tile[r][cl] = src[(size_t)(ta * 64 + r) * COUT + tb * 64 + cl];
        __syncthreads();
        for (int r = rw; r < 64; r += 4) {
            int co = tb * 64 + r;
            int ci = ta * 64 + cl;
            int ciw = swz ? ((ci & ~127) | ((ci & 127) ^ ((co & 7) << 3))) : ci;
            dst[(size_t)co * CIN + ciw] = f2h(tile[cl][r]);
        }
    } else {
        // -------- level-0 split (Ls = 512) --------
        const int Ls = 512;
        int idx = (blk - 3584) * 256 + tid;          // 1,048,576
        int row = idx >> 5;
        int cq  = (idx & 31) << 2;
        int BLs = B_ * Ls;
        int g  = row / BLs;
        int r2 = row - g * BLs;
        int b  = r2 / Ls;
        int u  = r2 - b * Ls;
        int p = g >> 1, i = g & 1;
        const float4 v = *(const float4*)(x +
            ((size_t)(p * B_ + b) * (2 * Ls) + 2 * u + i) * C_ + cq);
        ushort4 o;
        o.x = f2h(v.x); o.y = f2h(v.y); o.z = f2h(v.z); o.w = f2h(v.w);
        int cqw = cq ^ (((u + 4) & 7) << 3);
        *(ushort4*)(actb + (size_t)row * C_ + cqw) = o;
    }
}

// ---------------------------------------------------------------------------
// conv1 (weight-stationary, R12 form): out = leaky( conv_K5(in,W)+b1 ).
// 512 blocks (2/CU, resident). breg[5][2][4] half8 loaded once pre-loop;
// A: 2 x [80][128] LDS dbuf; rt sweep rotated by ct.
// Output hid swizzled key (t+2)&7 for conv2's LDS.
// ---------------------------------------------------------------------------
__global__ __launch_bounds__(256, 2)
void conv1_k(const unsigned short* __restrict__ actb,
             const unsigned short* __restrict__ wL,   // [widx][5][512][128] LINEAR
             const float* __restrict__ bias,          // [widx][512]
             unsigned short* __restrict__ hid,        // [G][B][Ls][512swz]
             const unsigned short* __restrict__ zp,
             int Ls, int rsplit, int idxbase) {
    __shared__ unsigned short smemA[2][80 * 128];     // 2 x 20 KiB

    const int tid = threadIdx.x;
    const int lane = tid & 63;
    const int w = tid >> 6;
    const int wr = w >> 1, wc = w & 1;

    const int blk = blockIdx.x;
    const int ct = blk & 7;                           // 8 col tiles of 64
    const int rs = (blk >> 3) % rsplit;
    const int g  = (blk >> 3) / rsplit;
    const int n0 = ct * 64;
    const int gin  = g ^ 1;
    const int widx = (idxbase + (g >> 1)) * 2 + (g & 1);

    const char* gbase = (const char*)(actb + (size_t)gin * B_ * Ls * C_);
    const float* bptr = bias + (size_t)widx * HID_;

    const unsigned short* wlane = wL + (size_t)widx * (K1_ * HID_ * C_)
        + (size_t)(n0 + wc * 32 + (lane & 15)) * C_ + ((lane >> 4) << 3);
    half8 breg[K1_][2][4];
#pragma unroll
    for (int t = 0; t < K1_; ++t)
#pragma unroll
        for (int n = 0; n < 2; ++n)
#pragma unroll
            for (int ks = 0; ks < 4; ++ks)
                breg[t][n][ks] = *(const half8*)(wlane
                    + ((size_t)t * HID_ + n * 16) * C_ + ks * 32);

    const float bv0 = bptr[n0 + wc * 32 + (lane & 15)];
    const float bv1 = bptr[n0 + wc * 32 + 16 + (lane & 15)];

    const int rtbase = rs * 8;
    const int i0 = ct & 7;                            // rotation offset

    auto stage = [&](int rt, int p) {
        const int b  = (rt * 64) / Ls;
        const int t0 = (rt * 64) % Ls;
        const char* inb = gbase + (size_t)b * Ls * 256;
#pragma unroll
        for (int j = 0; j < 5; ++j) {
            int ch = w * 5 + j;
            int q = ch * 1024 + lane * 16;
            int r = q >> 8;
            int cb = q & 255;
            int t = t0 - 4 + r;
            const char* src = (t >= 0) ? inb + (size_t)t * 256 + cb
                                       : (const char*)zp + cb;
            gload16(src, (char*)smemA[p] + ch * 1024);
        }
    };

    stage(rtbase + i0, 0);
    asm volatile("s_waitcnt vmcnt(0)" ::: "memory");
    __syncthreads();

#pragma unroll
    for (int i = 0; i < 8; ++i) {
        const int rt = rtbase + ((i + i0) & 7);       // rotated sweep
        const int b  = (rt * 64) / Ls;
        const int t0 = (rt * 64) % Ls;
        const int p  = i & 1;

        __syncthreads();                  // [A] all waves done reading buf[p^1]
        if (i < 7) stage(rtbase + ((i + 1 + i0) & 7), p ^ 1);
        if (i > 0) {
            if (i < 7) {
                asm volatile("s_waitcnt vmcnt(21)" ::: "memory");
            } else {
                asm volatile("s_waitcnt vmcnt(16)" ::: "memory");
            }
            __syncthreads();              // [B] buf[p] fully staged for everyone
        }

        f32x4 acc[2][2];
#pragma unroll
        for (int m = 0; m < 2; ++m)
#pragma unroll
            for (int n = 0; n < 2; ++n) acc[m][n] = (f32x4){0.f, 0.f, 0.f, 0.f};

        const unsigned short* sA = smemA[p];
#pragma unroll
        for (int kk = 0; kk < K1_; ++kk) {
#pragma unroll
            for (int ks = 0; ks < 4; ++ks) {
                half8 aF[2];
                const int cole = ks * 32 + ((lane >> 4) << 3);
#pragma unroll
                for (int m = 0; m < 2; ++m) {
                    int ar = kk + wr * 32 + m * 16 + (lane & 15);
                    aF[m] = *(const half8*)(sA + ar * 128 + (cole ^ ((ar & 7) << 3)));
                }
#pragma unroll
                for (int m = 0; m < 2; ++m) {
                    acc[m][0] = __builtin_amdgcn_mfma_f32_16x16x32_f16(
                        aF[m], breg[kk][0][ks], acc[m][0], 0, 0, 0);
                    acc[m][1] = __builtin_amdgcn_mfma_f32_16x16x32_f16(
                        aF[m], breg[kk][1][ks], acc[m][1], 0, 0, 0);
                }
            }
        }

        unsigned short* outp = hid + ((size_t)(g * B_ + b) * Ls + t0) * HID_;
#pragma unroll
        for (int n = 0; n < 2; ++n) {
            const int co = n0 + wc * 32 + n * 16 + (lane & 15);
            const float bv = n ? bv1 : bv0;
#pragma unroll
            for (int m = 0; m < 2; ++m) {
                const int u0 = wr * 32 + m * 16 + ((lane >> 4) << 2);
#pragma unroll
                for (int q = 0; q < 4; ++q) {
                    float v = acc[m][n][q] + bv;
                    v = (v > 0.f) ? v : 0.01f * v;        // LeakyReLU
                    int t = t0 + u0 + q;
                    int cow = (co & ~127) | ((co & 127) ^ (((t + 2) & 7) << 3));
                    outp[(size_t)(u0 + q) * HID_ + cow] = f2h(v);
                }
            }
        }
    }
}

// ---------------------------------------------------------------------------
// conv2 (R16 form): s = tanh( conv_K3(hid,W2)+b2 )
// tile 64 rows x 128 cols, 4 waves (2x2, wave tile 32x64), K = 3*512,
// rotated (ck,kk) rounds, LDS 49KB -> (256,3), all-fp16 carry.
// EPI 0: sv = ain (fp16 swz); mul = sv*exp(th) -> gout (fp16 swz (u+4)&7).
// EPI 1: val = gate +/- th -> actn (fused split, fp16 swz (uq+4)&7).
// EPI 2: val = gate +/- th -> dout (fused rev_split gather, f32).
// ---------------------------------------------------------------------------
template<int EPI>
__global__ __launch_bounds__(256, 3)
void conv2_k(const unsigned short* __restrict__ hid,  // [G][B][Ls][512swz]
             const unsigned short* __restrict__ wT,   // [widx][3][128][512swz]
             const float* __restrict__ bias,          // [widx][128]
             const unsigned short* __restrict__ ain,  // EPI==0: level input (swz)
             const unsigned short* __restrict__ gate, // EPI>=1 (fp16 swz)
             unsigned short* __restrict__ gout,       // EPI==0 out
             unsigned short* __restrict__ actn,       // EPI==1 next-lvl in
             float* __restrict__ dout,                // EPI==2 out
             const unsigned short* __restrict__ zp,
             int Ls, int RT, int idxbase) {
    __shared__ unsigned short smemA[66 * 128];
    __shared__ unsigned short smemB[128 * 128];

    const int tid = threadIdx.x;
    const int lane = tid & 63;
    const int w = tid >> 6;
    const int wr = w >> 1, wc = w & 1;

    int blk = blockIdx.x;
    const int rt = blk % RT;
    const int g  = blk / RT;
    const int rowstart = rt * 64;
    const int b  = rowstart / Ls;
    const int t0 = rowstart - b * Ls;
    const int widx = (idxbase + (g >> 1)) * 2 + (g & 1);

    const char* inb = (const char*)(hid + (size_t)(g * B_ + b) * Ls * HID_);
    const char* wb  = (const char*)(wT + (size_t)widx * (K2_ * C_ * HID_));
    const float* bptr = bias + (size_t)widx * C_;

    const int c0 = blk & 3;                           // rotation offsets
    const int k0 = blk % 3;

    f32x4 acc[2][4];
#pragma unroll
    for (int m = 0; m < 2; ++m)
#pragma unroll
        for (int n = 0; n < 4; ++n) acc[m][n] = (f32x4){0.f, 0.f, 0.f, 0.f};

    for (int ckp = 0; ckp < 4; ++ckp) {        // rotated chunks over CIN=512
        const int ck = (ckp + c0) & 3;
        if (ckp) __syncthreads();
        // stage A chunk: rows t0-2 .. t0+63 (66 rows x 256 B = 16896 B)
        for (int ch = w; ch < 17; ch += 4) {
            int q = ch * 1024 + lane * 16;
            if (q < 16896) {
                int r = q >> 8;
                int cb = q & 255;
                int t = t0 - 2 + r;
                const char* src = (t >= 0)
                    ? inb + (size_t)t * 1024 + ck * 256 + cb
                    : (const char*)zp + cb;
                gload16(src, (char*)smemA + ch * 1024);
            }
        }
        for (int kkp = 0; kkp < K2_; ++kkp) {
            const int kk = (kkp + k0) % 3;
            if (kkp) __syncthreads();
            const char* wt = wb + (size_t)kk * C_ * HID_ * 2;
            for (int ch = w; ch < 32; ch += 4) {
                int q = ch * 1024 + lane * 16;
                int co = q >> 8;
                int cb = q & 255;
                gload16(wt + (size_t)co * 1024 + ck * 256 + cb,
                        (char*)smemB + ch * 1024);
            }
            asm volatile("s_waitcnt vmcnt(0)" ::: "memory");
            __syncthreads();

#pragma unroll
            for (int ks = 0; ks < 4; ++ks) {
                half8 aF[2], bF[4];
                const int cole = ks * 32 + ((lane >> 4) << 3);
#pragma unroll
                for (int m = 0; m < 2; ++m) {
                    int ar = kk + wr * 32 + m * 16 + (lane & 15);
                    aF[m] = *(const half8*)(smemA + ar * 128 + (cole ^ ((ar & 7) << 3)));
                }
#pragma unroll
                for (int n = 0; n < 4; ++n) {
                    int br = wc * 64 + n * 16 + (lane & 15);
                    bF[n] = *(const half8*)(smemB + br * 128 + (cole ^ ((br & 7) << 3)));
                }
#pragma unroll
                for (int m = 0; m < 2; ++m)
#pragma unroll
                    for (int n = 0; n < 4; ++n)
                        acc[m][n] = __builtin_amdgcn_mfma_f32_16x16x32_f16(
                            aF[m], bF[n], acc[m][n], 0, 0, 0);
            }
        }
    }

    const size_t rowb = (size_t)(g * B_ + b) * Ls + t0;
    const int Ls2 = Ls >> 1;
    const int i_ = g & 1;
#pragma unroll
    for (int n = 0; n < 4; ++n) {
        int c = wc * 64 + n * 16 + (lane & 15);
        float bv = bptr[c];
#pragma unroll
        for (int m = 0; m < 2; ++m) {
            int u0 = wr * 32 + m * 16 + ((lane >> 4) << 2);
#pragma unroll
            for (int q = 0; q < 4; ++q) {
                float v = acc[m][n][q] + bv;
                float xc = fminf(fmaxf(v, -15.f), 15.f);
                float e2 = __expf(2.f * xc);
                float th = (e2 - 1.f) / (e2 + 1.f);        // tanh
                size_t ro = rowb + (size_t)(u0 + q);
                int u = t0 + u0 + q;                       // local split time
                int cw = c ^ (((u + 4) & 7) << 3);         // fp16-buffer swizzle
                if (EPI == 0) {
                    float sv = h2f(ain[ro * C_ + cw]);     // level input (fp16)
                    float mv = sv * __expf(th);
                    gout[ro * C_ + cw] = f2h(mv);
                } else {
                    float mv = h2f(gate[ro * C_ + cw]);
                    float val = (i_ == 0) ? (mv + th) : (mv - th);
                    if (EPI == 1) {
                        int gq = g * 2 + (u & 1);          // fused split
                        int uq = u >> 1;
                        int cw2 = c ^ (((uq + 4) & 7) << 3);
                        actn[((size_t)(gq * B_ + b) * Ls2 + uq) * C_ + cw2] = f2h(val);
                    } else {
                        int tau = u | (((g >> 2) & 1) << 7) | (((g >> 1) & 1) << 8)
                                    | ((g & 1) << 9);
                        dout[((size_t)b * T_ + tau) * C_ + c] = val;
                    }
                }
            }
        }
    }
}

// ---------------------------------------------------------------------------
extern "C" void kernel_launch(void* const* d_in, const int* in_sizes, int n_in,
                              void* d_out, int out_size, void* d_ws, size_t ws_size,
                              hipStream_t stream) {
    const float* x   = (const float*)d_in[0];
    const float* mw1 = (const float*)d_in[1];
    const float* mb1 = (const float*)d_in[2];
    const float* mw2 = (const float*)d_in[3];
    const float* mb2 = (const float*)d_in[4];
    const float* aw1 = (const float*)d_in[5];
    const float* ab1 = (const float*)d_in[6];
    const float* aw2 = (const float*)d_in[7];
    const float* ab2 = (const float*)d_in[8];

    char* ws = (char*)d_ws;
    size_t off = 0;
    auto alloc = [&](size_t sz) {
        char* p = ws + off;
        off += (sz + 255) & ~(size_t)255;
        return p;
    };
    unsigned short* zp   = (unsigned short*)alloc(8192);
    unsigned short* w1m  = (unsigned short*)alloc((size_t)14 * 5 * 512 * 128 * 2);
    unsigned short* w1a  = (unsigned short*)alloc((size_t)14 * 5 * 512 * 128 * 2);
    unsigned short* w2m  = (unsigned short*)alloc((size_t)14 * 3 * 128 * 512 * 2);
    unsigned short* w2a  = (unsigned short*)alloc((size_t)14 * 3 * 128 * 512 * 2);
    unsigned short* actb = (unsigned short*)alloc((size_t)4194304 * 2);
    unsigned short* actg = (unsigned short*)alloc((size_t)4194304 * 2);
    unsigned short* hidb = (unsigned short*)alloc((size_t)16777216 * 2);
    (void)ws_size; (void)n_in; (void)in_sizes; (void)out_size;

    hipMemsetAsync(zp, 0, 8192, stream);

    // merged prep: w1 transpose (linear) + w2 transpose (swz) + level-0 split
    prep_k<<<7680, 256, 0, stream>>>(mw1, w1m, aw1, w1a,
                                     mw2, w2m, aw2, w2a, x, actb);

    for (int lvl = 0; lvl < 3; ++lvl) {
        const int G = 2 << lvl;
        const int Ls = (1024 >> lvl) >> 1;
        const int idxbase = (1 << lvl) - 1;
        const int rsplit = (B_ * Ls / 64) / 8;   // 8 row-tiles per conv1 block
        const int RT2 = Ls / 2;                  // conv2 64-row tiles

        // mul branch: conv1 reads actb -> hidb; conv2<0> reads actb -> actg
        conv1_k<<<512, 256, 0, stream>>>(actb, w1m, mb1, hidb, zp,
                                         Ls, rsplit, idxbase);
        conv2_k<0><<<G * RT2, 256, 0, stream>>>(hidb, w2m, mb2, actb, nullptr,
                                                actg, nullptr, nullptr,
                                                zp, Ls, RT2, idxbase);
        // add branch: conv1 reads actg -> hidb; conv2<1/2> combine from actg
        conv1_k<<<512, 256, 0, stream>>>(actg, w1a, ab1, hidb, zp,
                                         Ls, rsplit, idxbase);
        if (lvl < 2) {
            conv2_k<1><<<G * RT2, 256, 0, stream>>>(hidb, w2a, ab2, nullptr, actg,
                                                    nullptr, actb, nullptr,
                                                    zp, Ls, RT2, idxbase);
        } else {
            conv2_k<2><<<G * RT2, 256, 0, stream>>>(hidb, w2a, ab2, nullptr, actg,
                                                    nullptr, nullptr, (float*)d_out,
                                                    zp, Ls, RT2, idxbase);
        }
    }
}